// Round 6
// baseline (9507.394 us; speedup 1.0000x reference)
//
#include <hip/hip_runtime.h>
#include <hip/hip_bf16.h>
#include <hip/hip_cooperative_groups.h>

namespace cg = cooperative_groups;

#define SEQ    200
#define BATCH  128
#define NTN    97
#define NTD    300
#define TD     1200
#define HID    1500
#define PRED   97
#define INDIM  1500
#define KH     1536      /* padded HID (48*32) */
#define KX     1216      /* padded TD  (38*32) */
#define KA     320       /* padded NTD (10*32) */
#define NP     6144      /* padded 4*HID (192*32), gate rows permuted n'=4j+g */
#define NOUT   112       /* padded PRED */
#define MR     (SEQ*BATCH)

using bf16x8 = __attribute__((ext_vector_type(8))) __bf16;
using f32x4  = __attribute__((ext_vector_type(4))) float;

typedef __attribute__((address_space(1))) const void gvoid;
typedef __attribute__((address_space(3))) void lvoid;

__device__ __forceinline__ unsigned short f2bf(float f) {
  unsigned int u = __float_as_uint(f);
  u = (u + 0x7FFFu + ((u >> 16) & 1u)) >> 16;
  return (unsigned short)u;
}
__device__ __forceinline__ float bf2f(unsigned short s) {
  return __uint_as_float(((unsigned int)s) << 16);
}
__device__ __forceinline__ float sigm(float x) { return 1.f / (1.f + __expf(-x)); }
__device__ __forceinline__ float tanh_f(float x) {
  float e = __expf(-2.f * fabsf(x));
  float t = (1.f - e) / (1.f + e);
  return copysignf(t, x);
}

// ---------- weight conversion / permutation kernels ----------

// terminal part of W_ih -> bf16 [NP][KX], rows permuted n'=4j+g
__global__ __launch_bounds__(256) void k_wih_t(const float* __restrict__ W_ih,
                                               unsigned short* __restrict__ out) {
  int idx = blockIdx.x * 256 + threadIdx.x;   // NP*(KX/8)
  int np = idx / (KX / 8);
  int d0 = (idx - np * (KX / 8)) * 8;
  if (np >= NP) return;
  int j = np >> 2, g = np & 3;
  union { unsigned short s[8]; uint4 v; } u;
  if (j < HID && d0 < TD) {                   // TD%8==0: all-valid or all-pad
    const float* src = W_ih + (size_t)(g * HID + j) * INDIM + NTD + d0;
    float4 f0 = *(const float4*)src;
    float4 f1 = *(const float4*)(src + 4);
    u.s[0]=f2bf(f0.x); u.s[1]=f2bf(f0.y); u.s[2]=f2bf(f0.z); u.s[3]=f2bf(f0.w);
    u.s[4]=f2bf(f1.x); u.s[5]=f2bf(f1.y); u.s[6]=f2bf(f1.z); u.s[7]=f2bf(f1.w);
  } else {
    u.v = make_uint4(0, 0, 0, 0);
  }
  *(uint4*)(out + (size_t)np * KX + d0) = u.v;
}

// non-terminal part of W_ih -> bf16 [NP][KA]
__global__ __launch_bounds__(256) void k_wih_a(const float* __restrict__ W_ih,
                                               unsigned short* __restrict__ out) {
  int idx = blockIdx.x * 256 + threadIdx.x;   // NP*(KA/8)
  int np = idx / (KA / 8);
  int d0 = (idx - np * (KA / 8)) * 8;
  if (np >= NP) return;
  int j = np >> 2, g = np & 3;
  union { unsigned short s[8]; uint4 v; } u;
  #pragma unroll
  for (int q = 0; q < 8; ++q) {
    int d = d0 + q;
    float f = (j < HID && d < NTD) ? W_ih[(size_t)(g * HID + j) * INDIM + d] : 0.f;
    u.s[q] = f2bf(f);
  }
  *(uint4*)(out + (size_t)np * KA + d0) = u.v;
}

// W_hh -> bf16 [NP][KH], permuted
__global__ __launch_bounds__(256) void k_whh(const float* __restrict__ W_hh,
                                             unsigned short* __restrict__ out) {
  int idx = blockIdx.x * 256 + threadIdx.x;   // NP*(KH/8)
  int np = idx / (KH / 8);
  int d0 = (idx - np * (KH / 8)) * 8;
  if (np >= NP) return;
  int j = np >> 2, g = np & 3;
  union { unsigned short s[8]; uint4 v; } u;
  if (j < HID && d0 + 8 <= HID) {
    const float* src = W_hh + (size_t)(g * HID + j) * HID + d0;
    float4 f0 = *(const float4*)src;
    float4 f1 = *(const float4*)(src + 4);
    u.s[0]=f2bf(f0.x); u.s[1]=f2bf(f0.y); u.s[2]=f2bf(f0.z); u.s[3]=f2bf(f0.w);
    u.s[4]=f2bf(f1.x); u.s[5]=f2bf(f1.y); u.s[6]=f2bf(f1.z); u.s[7]=f2bf(f1.w);
  } else {
    #pragma unroll
    for (int q = 0; q < 8; ++q) {
      int d = d0 + q;
      float f = (j < HID && d < HID) ? W_hh[(size_t)(g * HID + j) * HID + d] : 0.f;
      u.s[q] = f2bf(f);
    }
  }
  *(uint4*)(out + (size_t)np * KH + d0) = u.v;
}

// W_out -> bf16 [NOUT][KH]
__global__ __launch_bounds__(256) void k_wout(const float* __restrict__ W_out,
                                              unsigned short* __restrict__ out) {
  int idx = blockIdx.x * 256 + threadIdx.x;   // NOUT*(KH/8) = 21504
  if (idx >= NOUT * (KH / 8)) return;
  int n = idx / (KH / 8);
  int d0 = (idx - n * (KH / 8)) * 8;
  union { unsigned short s[8]; uint4 v; } u;
  #pragma unroll
  for (int q = 0; q < 8; ++q) {
    int d = d0 + q;
    float f = (n < PRED && d < HID) ? W_out[(size_t)n * HID + d] : 0.f;
    u.s[q] = f2bf(f);
  }
  *(uint4*)(out + (size_t)n * KH + d0) = u.v;
}

// nt_emb -> bf16 [128][KA] (rows >=97 zero)
__global__ __launch_bounds__(256) void k_ntemb(const float* __restrict__ nt_emb,
                                               unsigned short* __restrict__ out) {
  int idx = blockIdx.x * 256 + threadIdx.x;   // 128*(KA/8) = 5120
  if (idx >= 128 * (KA / 8)) return;
  int v = idx / (KA / 8);
  int d0 = (idx - v * (KA / 8)) * 8;
  union { unsigned short s[8]; uint4 vv; } u;
  #pragma unroll
  for (int q = 0; q < 8; ++q) {
    int d = d0 + q;
    float f = (v < NTN && d < NTD) ? nt_emb[(size_t)v * NTD + d] : 0.f;
    u.s[q] = f2bf(f);
  }
  *(uint4*)(out + (size_t)v * KA + d0) = u.vv;
}

// gather terminal embeddings -> X bf16 [MR][KX]
__global__ __launch_bounds__(256) void k_xgather(const int* __restrict__ tids,
                                                 const float* __restrict__ t_emb,
                                                 unsigned short* __restrict__ X) {
  int idx = blockIdx.x * 256 + threadIdx.x;   // MR*(KX/8)
  int r = idx / (KX / 8);
  int d0 = (idx - r * (KX / 8)) * 8;
  if (r >= MR) return;
  union { unsigned short s[8]; uint4 v; } u;
  if (d0 < TD) {                               // TD%8==0
    const float* src = t_emb + (size_t)tids[r] * TD + d0;
    float4 f0 = *(const float4*)src;
    float4 f1 = *(const float4*)(src + 4);
    u.s[0]=f2bf(f0.x); u.s[1]=f2bf(f0.y); u.s[2]=f2bf(f0.z); u.s[3]=f2bf(f0.w);
    u.s[4]=f2bf(f1.x); u.s[5]=f2bf(f1.y); u.s[6]=f2bf(f1.z); u.s[7]=f2bf(f1.w);
  } else {
    u.v = make_uint4(0, 0, 0, 0);
  }
  *(uint4*)(X + (size_t)r * KX + d0) = u.v;
}

// init hs[0] (bf16, padded) and c_ws (f32, padded), applying forget_vector
__global__ __launch_bounds__(256) void k_init(const float* __restrict__ h0,
                                              const float* __restrict__ c0,
                                              const float* __restrict__ fv,
                                              unsigned short* __restrict__ hs,
                                              float* __restrict__ cws) {
  int idx = blockIdx.x * 256 + threadIdx.x;   // 128*KH
  int b = idx / KH, j = idx - b * KH;
  if (b >= BATCH) return;
  float fvb = fv[b];
  float h = (j < HID) ? h0[(size_t)b * HID + j] * fvb : 0.f;
  float c = (j < HID) ? c0[(size_t)b * HID + j] * fvb : 0.f;
  hs[(size_t)b * KH + j] = f2bf(h);
  cws[(size_t)b * KH + j] = c;
}

// ---------- big GEMM: C = A[M,KP] * B[N,KP]^T  (both bf16, row-major over K) ----------
// EPI=0: out bf16 gates_x, += nt_table[ntid[row]][col]
// EPI=1: out f32 nt_table, += b_ih[orig]+b_hh[orig]
template <int KP, int EPI>
__global__ __launch_bounds__(256)
void gemm_bt(const unsigned short* __restrict__ A,
             const unsigned short* __restrict__ B,
             void* __restrict__ outp, int Mtiles,
             const int* __restrict__ ntid,
             const float* __restrict__ nt_table,
             const float* __restrict__ b_ih,
             const float* __restrict__ b_hh) {
  __shared__ unsigned short Asm_[128 * 64];
  __shared__ unsigned short Bsm_[128 * 64];
  const int tid = threadIdx.x;
  const int bid = blockIdx.x;
  const int chunk = gridDim.x >> 3;
  int swz = (bid & 7) * chunk + (bid >> 3);   // XCD-aware (gridDim%8==0)
  const int mt = swz % Mtiles;
  const int nt = swz / Mtiles;
  const int m0 = mt * 128, n0 = nt * 128;
  const int w = tid >> 6, lane = tid & 63;
  const int wr = w >> 1, wc = w & 1;
  const int l15 = lane & 15, l4 = lane >> 4;

  f32x4 acc[4][4] = {};

  for (int kt = 0; kt < KP / 64; ++kt) {
    #pragma unroll
    for (int q = 0; q < 4; ++q) {
      int c = q * 256 + tid;
      int row = c >> 3;
      int kb = (c & 7) << 4;
      const char* ga = (const char*)A + ((size_t)(m0 + row) * KP + kt * 64) * 2 + kb;
      const char* gb = (const char*)B + ((size_t)(n0 + row) * KP + kt * 64) * 2 + kb;
      __builtin_amdgcn_global_load_lds((gvoid*)ga, (lvoid*)((char*)Asm_ + c * 16), 16, 0, 0);
      __builtin_amdgcn_global_load_lds((gvoid*)gb, (lvoid*)((char*)Bsm_ + c * 16), 16, 0, 0);
    }
    __syncthreads();
    #pragma unroll
    for (int ks = 0; ks < 2; ++ks) {
      bf16x8 av[4], bv[4];
      #pragma unroll
      for (int i = 0; i < 4; ++i) {
        av[i] = *(const bf16x8*)&Asm_[(wr * 64 + i * 16 + l15) * 64 + ks * 32 + l4 * 8];
        bv[i] = *(const bf16x8*)&Bsm_[(wc * 64 + i * 16 + l15) * 64 + ks * 32 + l4 * 8];
      }
      #pragma unroll
      for (int i = 0; i < 4; ++i)
        #pragma unroll
        for (int jj = 0; jj < 4; ++jj)
          acc[i][jj] = __builtin_amdgcn_mfma_f32_16x16x32_bf16(av[i], bv[jj], acc[i][jj], 0, 0, 0);
    }
    __syncthreads();
  }

  if constexpr (EPI == 0) {
    unsigned short* out = (unsigned short*)outp;
    #pragma unroll
    for (int i = 0; i < 4; ++i) {
      #pragma unroll
      for (int jj = 0; jj < 4; ++jj) {
        int col = n0 + wc * 64 + jj * 16 + l15;
        #pragma unroll
        for (int r = 0; r < 4; ++r) {
          int row = m0 + wr * 64 + i * 16 + l4 * 4 + r;
          float v = acc[i][jj][r] + nt_table[(size_t)ntid[row] * NP + col];
          out[(size_t)row * NP + col] = f2bf(v);
        }
      }
    }
  } else {
    float* out = (float*)outp;
    #pragma unroll
    for (int i = 0; i < 4; ++i) {
      #pragma unroll
      for (int jj = 0; jj < 4; ++jj) {
        int col = n0 + wc * 64 + jj * 16 + l15;
        int unit = col >> 2, gt = col & 3;
        float bias = (unit < HID) ? (b_ih[gt * HID + unit] + b_hh[gt * HID + unit]) : 0.f;
        #pragma unroll
        for (int r = 0; r < 4; ++r) {
          int row = m0 + wr * 64 + i * 16 + l4 * 4 + r;
          out[(size_t)row * NP + col] = acc[i][jj][r] + bias;
        }
      }
    }
  }
}

// ---------- cooperative LSTM recurrence: 192 blocks x 256 thr, 1 grid.sync/step ----------
// block nb owns gate cols n'=[32nb,32nb+32) == hidden units [8nb,8nb+8)
// 4 waves, wave w = batch rows [32w,32w+32) x all 32 gate cols (Mg=4,Ng=1):
// W-LDS traffic 384KB/step (vs 768KB at 8 waves), h read exactly once per block.
__global__ __launch_bounds__(256)
void lstm_coop(const unsigned short* __restrict__ gates_x,
               const unsigned short* __restrict__ Whh,
               unsigned short* __restrict__ hs,
               float* __restrict__ cws) {
  extern __shared__ char smem[];
  // [0,98304): W slice bf16 [32][KH], XOR-swizzled; [98304,106496): gx bf16 [128][32];
  // [106496,122880): gates f32 [128][32]
  unsigned short* gxs = (unsigned short*)(smem + 98304);
  float* gsh = (float*)(smem + 106496);

  const int tid = threadIdx.x;
  const int nb = blockIdx.x;
  const int n0 = nb * 32;

  for (int c = tid; c < 32 * 192; c += 256) {   // preload W slice (once, stays resident)
    int row = c / 192;
    int kb = (c - row * 192) * 16;
    uint4 v = *(const uint4*)((const char*)Whh + ((size_t)(n0 + row) * KH) * 2 + kb);
    *(uint4*)(smem + row * 3072 + (kb ^ ((row & 7) << 4))) = v;
  }
  __syncthreads();

  const int w = tid >> 6, lane = tid & 63;
  const int l15 = lane & 15, l4 = lane >> 4;
  const int mrow = w * 32;                      // 32 batch rows per wave
  const int sw = (l15 & 7) << 4;

  cg::grid_group grid = cg::this_grid();

  for (int t = 0; t < SEQ; ++t) {
    // stage gates_x tile: issue loads early (2 x uint4 per thread), write to LDS late
    const int it0 = tid, it1 = 256 + tid;       // [128 rows][4 x 16B chunks]
    uint4 gxv0 = *(const uint4*)((const char*)gates_x +
                                 ((size_t)(t * BATCH + (it0 >> 2)) * NP + n0) * 2 + (it0 & 3) * 16);
    uint4 gxv1 = *(const uint4*)((const char*)gates_x +
                                 ((size_t)(t * BATCH + (it1 >> 2)) * NP + n0) * 2 + (it1 & 3) * 16);

    const char* ap0 = (const char*)hs + ((size_t)t * BATCH + mrow + l15) * KH * 2 + l4 * 16;
    const char* ap1 = ap0 + (size_t)16 * KH * 2;
    const char* b0base = smem + l15 * 3072;
    const char* b1base = smem + (16 + l15) * 3072;

    f32x4 acc00 = {0.f,0.f,0.f,0.f}, acc01 = {0.f,0.f,0.f,0.f};
    f32x4 acc10 = {0.f,0.f,0.f,0.f}, acc11 = {0.f,0.f,0.f,0.f};
    #pragma unroll 8
    for (int kk = 0; kk < KH / 32; ++kk) {
      int koff = kk * 64 + l4 * 16;
      bf16x8 a0 = *(const bf16x8*)(ap0 + kk * 64);
      bf16x8 a1 = *(const bf16x8*)(ap1 + kk * 64);
      bf16x8 b0 = *(const bf16x8*)(b0base + (koff ^ sw));
      bf16x8 b1 = *(const bf16x8*)(b1base + (koff ^ sw));
      acc00 = __builtin_amdgcn_mfma_f32_16x16x32_bf16(a0, b0, acc00, 0, 0, 0);
      acc01 = __builtin_amdgcn_mfma_f32_16x16x32_bf16(a0, b1, acc01, 0, 0, 0);
      acc10 = __builtin_amdgcn_mfma_f32_16x16x32_bf16(a1, b0, acc10, 0, 0, 0);
      acc11 = __builtin_amdgcn_mfma_f32_16x16x32_bf16(a1, b1, acc11, 0, 0, 0);
    }

    *(uint4*)((char*)gxs + (it0 >> 2) * 64 + (it0 & 3) * 16) = gxv0;
    *(uint4*)((char*)gxs + (it1 >> 2) * 64 + (it1 & 3) * 16) = gxv1;
    #pragma unroll
    for (int r = 0; r < 4; ++r) {
      gsh[(mrow +      l4 * 4 + r) * 32 +      l15] = acc00[r];
      gsh[(mrow +      l4 * 4 + r) * 32 + 16 + l15] = acc01[r];
      gsh[(mrow + 16 + l4 * 4 + r) * 32 +      l15] = acc10[r];
      gsh[(mrow + 16 + l4 * 4 + r) * 32 + 16 + l15] = acc11[r];
    }
    __syncthreads();

    unsigned short* hnext = hs + (size_t)(t + 1) * BATCH * KH;
    #pragma unroll
    for (int q = 0; q < 4; ++q) {
      int it = q * 256 + tid;                   // 128 batch x 8 units
      int m = it >> 3, dj = it & 7;
      float4 gv = *(const float4*)&gsh[m * 32 + dj * 4];
      const unsigned short* gp = gxs + m * 32 + dj * 4;
      float gi = gv.x + bf2f(gp[0]);
      float gf = gv.y + bf2f(gp[1]);
      float gg = gv.z + bf2f(gp[2]);
      float go = gv.w + bf2f(gp[3]);
      int j = (n0 >> 2) + dj;
      float c_old = cws[(size_t)m * KH + j];
      float cn = sigm(gf) * c_old + sigm(gi) * tanh_f(gg);
      float hn = sigm(go) * tanh_f(cn);
      cws[(size_t)m * KH + j] = cn;
      hnext[(size_t)m * KH + j] = f2bf(hn);
    }
    grid.sync();
  }
}

// ---------- output projection + log_softmax ----------
__global__ __launch_bounds__(256)
void out_softmax(const unsigned short* __restrict__ hs1,
                 const unsigned short* __restrict__ Wout,
                 const float* __restrict__ b_out,
                 float* __restrict__ pred) {
  const int tid = threadIdx.x;
  const int blk = blockIdx.x;   // 200
  const int w = tid >> 6, lane = tid & 63;
  const int l15 = lane & 15, l4 = lane >> 4;
  const int m0 = blk * 128 + w * 32;

  f32x4 acc[2][7] = {};
  const char* a0p = (const char*)hs1 + ((size_t)(m0 + l15)) * KH * 2 + l4 * 16;
  const char* a1p = a0p + (size_t)16 * KH * 2;
  const char* bp = (const char*)Wout + ((size_t)l15) * KH * 2 + l4 * 16;

  for (int kk = 0; kk < KH / 32; ++kk) {
    bf16x8 a0 = *(const bf16x8*)(a0p + kk * 64);
    bf16x8 a1 = *(const bf16x8*)(a1p + kk * 64);
    #pragma unroll
    for (int ni = 0; ni < 7; ++ni) {
      bf16x8 b = *(const bf16x8*)(bp + (size_t)ni * 16 * KH * 2 + kk * 64);
      acc[0][ni] = __builtin_amdgcn_mfma_f32_16x16x32_bf16(a0, b, acc[0][ni], 0, 0, 0);
      acc[1][ni] = __builtin_amdgcn_mfma_f32_16x16x32_bf16(a1, b, acc[1][ni], 0, 0, 0);
    }
  }

  #pragma unroll
  for (int mi = 0; mi < 2; ++mi) {
    #pragma unroll
    for (int r = 0; r < 4; ++r) {
      float vals[7];
      float mx = -3.0e38f;
      #pragma unroll
      for (int ni = 0; ni < 7; ++ni) {
        int col = ni * 16 + l15;
        float v = acc[mi][ni][r];
        if (col < PRED) { v += b_out[col]; mx = fmaxf(mx, v); }
        vals[ni] = v;
      }
      #pragma unroll
      for (int s = 1; s < 16; s <<= 1) mx = fmaxf(mx, __shfl_xor(mx, s));
      float se = 0.f;
      #pragma unroll
      for (int ni = 0; ni < 7; ++ni) {
        int col = ni * 16 + l15;
        if (col < PRED) se += __expf(vals[ni] - mx);
      }
      #pragma unroll
      for (int s = 1; s < 16; s <<= 1) se += __shfl_xor(se, s);
      float lse = __logf(se) + mx;
      int row = m0 + mi * 16 + l4 * 4 + r;
      #pragma unroll
      for (int ni = 0; ni < 7; ++ni) {
        int col = ni * 16 + l15;
        if (col < PRED) pred[(size_t)row * PRED + col] = vals[ni] - lse;
      }
    }
  }
}

// final h, c outputs
__global__ __launch_bounds__(256) void k_hc_out(const unsigned short* __restrict__ hs200,
                                                const float* __restrict__ cws,
                                                float* __restrict__ out_h,
                                                float* __restrict__ out_c) {
  int idx = blockIdx.x * 256 + threadIdx.x;   // 128*KH
  int b = idx / KH, j = idx - b * KH;
  if (b >= BATCH || j >= HID) return;
  out_h[(size_t)b * HID + j] = bf2f(hs200[(size_t)b * KH + j]);
  out_c[(size_t)b * HID + j] = cws[(size_t)b * KH + j];
}

// ---------- workspace layout (bytes) ----------
#define OFF_GX    0ull                     /* bf16 [MR][NP]      314,572,800 */
#define OFF_WIHT  314572800ull             /* bf16 [NP][KX]       14,942,208 */
#define OFF_WIHA  329515008ull             /* bf16 [NP][KA]        3,932,160 */
#define OFF_WHH   333447168ull             /* bf16 [NP][KH]       18,874,368 */
#define OFF_WOUT  352321536ull             /* bf16 [NOUT][KH]        344,064 */
#define OFF_NTT   352665600ull             /* f32  [128][NP]       3,145,728 */
#define OFF_NTEB  355811328ull             /* bf16 [128][KA]          81,920 */
#define OFF_CWS   355893248ull             /* f32  [128][KH]         786,432 */
#define OFF_HS    356679680ull             /* bf16 [201][128][KH] 79,036,416 */
#define OFF_X     356679680ull             /* bf16 [MR][KX] aliases HS (dead before HS init) */

extern "C" void kernel_launch(void* const* d_in, const int* in_sizes, int n_in,
                              void* d_out, int out_size, void* d_ws, size_t ws_size,
                              hipStream_t stream) {
  (void)in_sizes; (void)n_in; (void)out_size; (void)ws_size;
  const int*   nt_in  = (const int*)  d_in[0];
  const int*   t_in   = (const int*)  d_in[1];
  const float* h0     = (const float*)d_in[2];
  const float* c0     = (const float*)d_in[3];
  const float* fv     = (const float*)d_in[4];
  const float* nt_emb = (const float*)d_in[5];
  const float* t_emb  = (const float*)d_in[6];
  const float* W_ih   = (const float*)d_in[7];
  const float* W_hh   = (const float*)d_in[8];
  const float* b_ih   = (const float*)d_in[9];
  const float* b_hh   = (const float*)d_in[10];
  const float* W_out  = (const float*)d_in[11];
  const float* b_out  = (const float*)d_in[12];

  char* ws = (char*)d_ws;
  unsigned short* gx    = (unsigned short*)(ws + OFF_GX);
  unsigned short* wih_t = (unsigned short*)(ws + OFF_WIHT);
  unsigned short* wih_a = (unsigned short*)(ws + OFF_WIHA);
  unsigned short* whh   = (unsigned short*)(ws + OFF_WHH);
  unsigned short* wout  = (unsigned short*)(ws + OFF_WOUT);
  float*          ntt   = (float*)(ws + OFF_NTT);
  unsigned short* nteb  = (unsigned short*)(ws + OFF_NTEB);
  float*          cws   = (float*)(ws + OFF_CWS);
  unsigned short* hs    = (unsigned short*)(ws + OFF_HS);
  unsigned short* X     = (unsigned short*)(ws + OFF_X);

  float* pred  = (float*)d_out;
  float* out_h = pred + (size_t)MR * PRED;
  float* out_c = out_h + (size_t)BATCH * HID;

  k_wih_t<<<3648, 256, 0, stream>>>(W_ih, wih_t);
  k_wih_a<<<960, 256, 0, stream>>>(W_ih, wih_a);
  k_whh<<<4608, 256, 0, stream>>>(W_hh, whh);
  k_wout<<<84, 256, 0, stream>>>(W_out, wout);
  k_ntemb<<<20, 256, 0, stream>>>(nt_emb, nteb);
  gemm_bt<KA, 1><<<48, 256, 0, stream>>>(nteb, wih_a, ntt, 1, nullptr, nullptr, b_ih, b_hh);
  k_xgather<<<15200, 256, 0, stream>>>(t_in, t_emb, X);
  gemm_bt<KX, 0><<<9600, 256, 0, stream>>>(X, wih_t, gx, 200, nt_in, ntt, nullptr, nullptr);
  k_init<<<768, 256, 0, stream>>>(h0, c0, fv, hs, cws);

  hipFuncSetAttribute((const void*)lstm_coop, hipFuncAttributeMaxDynamicSharedMemorySize, 122880);
  void* args[] = { (void*)&gx, (void*)&whh, (void*)&hs, (void*)&cws };
  hipLaunchCooperativeKernel((void*)lstm_coop, dim3(192), dim3(256), args, 122880, stream);

  out_softmax<<<200, 256, 0, stream>>>(hs + (size_t)BATCH * KH, wout, b_out, pred);
  k_hc_out<<<768, 256, 0, stream>>>(hs + (size_t)SEQ * BATCH * KH, cws, out_h, out_c);
}

// Round 8
// 7174.046 us; speedup vs baseline: 1.3252x; 1.3252x over previous
//
#include <hip/hip_runtime.h>
#include <hip/hip_bf16.h>
#include <hip/hip_cooperative_groups.h>

namespace cg = cooperative_groups;

#define SEQ    200
#define BATCH  128
#define NTN    97
#define NTD    300
#define TD     1200
#define HID    1500
#define PRED   97
#define INDIM  1500
#define KH     1536      /* padded HID (48*32) */
#define KX     1216      /* padded TD  (38*32) */
#define KA     320       /* padded NTD (10*32) */
#define NP     6144      /* padded 4*HID (192*32), gate rows permuted n'=4j+g */
#define NOUT   112       /* padded PRED */
#define MR     (SEQ*BATCH)

using bf16x8 = __attribute__((ext_vector_type(8))) __bf16;
using f32x4  = __attribute__((ext_vector_type(4))) float;

typedef __attribute__((address_space(1))) const void gvoid;
typedef __attribute__((address_space(3))) void lvoid;

__device__ __forceinline__ unsigned short f2bf(float f) {
  unsigned int u = __float_as_uint(f);
  u = (u + 0x7FFFu + ((u >> 16) & 1u)) >> 16;
  return (unsigned short)u;
}
__device__ __forceinline__ float bf2f(unsigned short s) {
  return __uint_as_float(((unsigned int)s) << 16);
}
__device__ __forceinline__ float sigm(float x) { return 1.f / (1.f + __expf(-x)); }
__device__ __forceinline__ float tanh_f(float x) {
  float e = __expf(-2.f * fabsf(x));
  float t = (1.f - e) / (1.f + e);
  return copysignf(t, x);
}
__device__ __forceinline__ void wait_vm(int n) {  // n is compile-time constant after unroll
  switch (n) {
    case 0: asm volatile("s_waitcnt vmcnt(0)" ::: "memory"); break;
    case 2: asm volatile("s_waitcnt vmcnt(2)" ::: "memory"); break;
    case 4: asm volatile("s_waitcnt vmcnt(4)" ::: "memory"); break;
    case 6: asm volatile("s_waitcnt vmcnt(6)" ::: "memory"); break;
    default: asm volatile("s_waitcnt vmcnt(8)" ::: "memory"); break;
  }
}

// ---------- weight conversion / permutation kernels ----------

__global__ __launch_bounds__(256) void k_wih_t(const float* __restrict__ W_ih,
                                               unsigned short* __restrict__ out) {
  int idx = blockIdx.x * 256 + threadIdx.x;   // NP*(KX/8)
  int np = idx / (KX / 8);
  int d0 = (idx - np * (KX / 8)) * 8;
  if (np >= NP) return;
  int j = np >> 2, g = np & 3;
  union { unsigned short s[8]; uint4 v; } u;
  if (j < HID && d0 < TD) {
    const float* src = W_ih + (size_t)(g * HID + j) * INDIM + NTD + d0;
    float4 f0 = *(const float4*)src;
    float4 f1 = *(const float4*)(src + 4);
    u.s[0]=f2bf(f0.x); u.s[1]=f2bf(f0.y); u.s[2]=f2bf(f0.z); u.s[3]=f2bf(f0.w);
    u.s[4]=f2bf(f1.x); u.s[5]=f2bf(f1.y); u.s[6]=f2bf(f1.z); u.s[7]=f2bf(f1.w);
  } else {
    u.v = make_uint4(0, 0, 0, 0);
  }
  *(uint4*)(out + (size_t)np * KX + d0) = u.v;
}

__global__ __launch_bounds__(256) void k_wih_a(const float* __restrict__ W_ih,
                                               unsigned short* __restrict__ out) {
  int idx = blockIdx.x * 256 + threadIdx.x;   // NP*(KA/8)
  int np = idx / (KA / 8);
  int d0 = (idx - np * (KA / 8)) * 8;
  if (np >= NP) return;
  int j = np >> 2, g = np & 3;
  union { unsigned short s[8]; uint4 v; } u;
  #pragma unroll
  for (int q = 0; q < 8; ++q) {
    int d = d0 + q;
    float f = (j < HID && d < NTD) ? W_ih[(size_t)(g * HID + j) * INDIM + d] : 0.f;
    u.s[q] = f2bf(f);
  }
  *(uint4*)(out + (size_t)np * KA + d0) = u.v;
}

__global__ __launch_bounds__(256) void k_whh(const float* __restrict__ W_hh,
                                             unsigned short* __restrict__ out) {
  int idx = blockIdx.x * 256 + threadIdx.x;   // NP*(KH/8)
  int np = idx / (KH / 8);
  int d0 = (idx - np * (KH / 8)) * 8;
  if (np >= NP) return;
  int j = np >> 2, g = np & 3;
  union { unsigned short s[8]; uint4 v; } u;
  if (j < HID && d0 + 8 <= HID) {
    const float* src = W_hh + (size_t)(g * HID + j) * HID + d0;
    float4 f0 = *(const float4*)src;
    float4 f1 = *(const float4*)(src + 4);
    u.s[0]=f2bf(f0.x); u.s[1]=f2bf(f0.y); u.s[2]=f2bf(f0.z); u.s[3]=f2bf(f0.w);
    u.s[4]=f2bf(f1.x); u.s[5]=f2bf(f1.y); u.s[6]=f2bf(f1.z); u.s[7]=f2bf(f1.w);
  } else {
    #pragma unroll
    for (int q = 0; q < 8; ++q) {
      int d = d0 + q;
      float f = (j < HID && d < HID) ? W_hh[(size_t)(g * HID + j) * HID + d] : 0.f;
      u.s[q] = f2bf(f);
    }
  }
  *(uint4*)(out + (size_t)np * KH + d0) = u.v;
}

__global__ __launch_bounds__(256) void k_wout(const float* __restrict__ W_out,
                                              unsigned short* __restrict__ out) {
  int idx = blockIdx.x * 256 + threadIdx.x;   // NOUT*(KH/8) = 21504
  if (idx >= NOUT * (KH / 8)) return;
  int n = idx / (KH / 8);
  int d0 = (idx - n * (KH / 8)) * 8;
  union { unsigned short s[8]; uint4 v; } u;
  #pragma unroll
  for (int q = 0; q < 8; ++q) {
    int d = d0 + q;
    float f = (n < PRED && d < HID) ? W_out[(size_t)n * HID + d] : 0.f;
    u.s[q] = f2bf(f);
  }
  *(uint4*)(out + (size_t)n * KH + d0) = u.v;
}

__global__ __launch_bounds__(256) void k_ntemb(const float* __restrict__ nt_emb,
                                               unsigned short* __restrict__ out) {
  int idx = blockIdx.x * 256 + threadIdx.x;   // 128*(KA/8) = 5120
  if (idx >= 128 * (KA / 8)) return;
  int v = idx / (KA / 8);
  int d0 = (idx - v * (KA / 8)) * 8;
  union { unsigned short s[8]; uint4 vv; } u;
  #pragma unroll
  for (int q = 0; q < 8; ++q) {
    int d = d0 + q;
    float f = (v < NTN && d < NTD) ? nt_emb[(size_t)v * NTD + d] : 0.f;
    u.s[q] = f2bf(f);
  }
  *(uint4*)(out + (size_t)v * KA + d0) = u.vv;
}

__global__ __launch_bounds__(256) void k_xgather(const int* __restrict__ tids,
                                                 const float* __restrict__ t_emb,
                                                 unsigned short* __restrict__ X) {
  int idx = blockIdx.x * 256 + threadIdx.x;   // MR*(KX/8)
  int r = idx / (KX / 8);
  int d0 = (idx - r * (KX / 8)) * 8;
  if (r >= MR) return;
  union { unsigned short s[8]; uint4 v; } u;
  if (d0 < TD) {
    const float* src = t_emb + (size_t)tids[r] * TD + d0;
    float4 f0 = *(const float4*)src;
    float4 f1 = *(const float4*)(src + 4);
    u.s[0]=f2bf(f0.x); u.s[1]=f2bf(f0.y); u.s[2]=f2bf(f0.z); u.s[3]=f2bf(f0.w);
    u.s[4]=f2bf(f1.x); u.s[5]=f2bf(f1.y); u.s[6]=f2bf(f1.z); u.s[7]=f2bf(f1.w);
  } else {
    u.v = make_uint4(0, 0, 0, 0);
  }
  *(uint4*)(X + (size_t)r * KX + d0) = u.v;
}

__global__ __launch_bounds__(256) void k_init(const float* __restrict__ h0,
                                              const float* __restrict__ c0,
                                              const float* __restrict__ fv,
                                              unsigned short* __restrict__ hs,
                                              float* __restrict__ cws) {
  int idx = blockIdx.x * 256 + threadIdx.x;   // 128*KH
  int b = idx / KH, j = idx - b * KH;
  if (b >= BATCH) return;
  float fvb = fv[b];
  float h = (j < HID) ? h0[(size_t)b * HID + j] * fvb : 0.f;
  float c = (j < HID) ? c0[(size_t)b * HID + j] * fvb : 0.f;
  hs[(size_t)b * KH + j] = f2bf(h);
  cws[(size_t)b * KH + j] = c;
}

// ---------- big GEMM: C = A[M,KP] * B[N,KP]^T ----------
template <int KP, int EPI>
__global__ __launch_bounds__(256)
void gemm_bt(const unsigned short* __restrict__ A,
             const unsigned short* __restrict__ B,
             void* __restrict__ outp, int Mtiles,
             const int* __restrict__ ntid,
             const float* __restrict__ nt_table,
             const float* __restrict__ b_ih,
             const float* __restrict__ b_hh) {
  __shared__ unsigned short Asm_[128 * 64];
  __shared__ unsigned short Bsm_[128 * 64];
  const int tid = threadIdx.x;
  const int bid = blockIdx.x;
  const int chunk = gridDim.x >> 3;
  int swz = (bid & 7) * chunk + (bid >> 3);   // XCD-aware (gridDim%8==0)
  const int mt = swz % Mtiles;
  const int nt = swz / Mtiles;
  const int m0 = mt * 128, n0 = nt * 128;
  const int w = tid >> 6, lane = tid & 63;
  const int wr = w >> 1, wc = w & 1;
  const int l15 = lane & 15, l4 = lane >> 4;

  f32x4 acc[4][4] = {};

  for (int kt = 0; kt < KP / 64; ++kt) {
    #pragma unroll
    for (int q = 0; q < 4; ++q) {
      int c = q * 256 + tid;
      int row = c >> 3;
      int kb = (c & 7) << 4;
      const char* ga = (const char*)A + ((size_t)(m0 + row) * KP + kt * 64) * 2 + kb;
      const char* gb = (const char*)B + ((size_t)(n0 + row) * KP + kt * 64) * 2 + kb;
      __builtin_amdgcn_global_load_lds((gvoid*)ga, (lvoid*)((char*)Asm_ + c * 16), 16, 0, 0);
      __builtin_amdgcn_global_load_lds((gvoid*)gb, (lvoid*)((char*)Bsm_ + c * 16), 16, 0, 0);
    }
    __syncthreads();
    #pragma unroll
    for (int ks = 0; ks < 2; ++ks) {
      bf16x8 av[4], bv[4];
      #pragma unroll
      for (int i = 0; i < 4; ++i) {
        av[i] = *(const bf16x8*)&Asm_[(wr * 64 + i * 16 + l15) * 64 + ks * 32 + l4 * 8];
        bv[i] = *(const bf16x8*)&Bsm_[(wc * 64 + i * 16 + l15) * 64 + ks * 32 + l4 * 8];
      }
      #pragma unroll
      for (int i = 0; i < 4; ++i)
        #pragma unroll
        for (int jj = 0; jj < 4; ++jj)
          acc[i][jj] = __builtin_amdgcn_mfma_f32_16x16x32_bf16(av[i], bv[jj], acc[i][jj], 0, 0, 0);
    }
    __syncthreads();
  }

  if constexpr (EPI == 0) {
    unsigned short* out = (unsigned short*)outp;
    #pragma unroll
    for (int i = 0; i < 4; ++i) {
      #pragma unroll
      for (int jj = 0; jj < 4; ++jj) {
        int col = n0 + wc * 64 + jj * 16 + l15;
        #pragma unroll
        for (int r = 0; r < 4; ++r) {
          int row = m0 + wr * 64 + i * 16 + l4 * 4 + r;
          float v = acc[i][jj][r] + nt_table[(size_t)ntid[row] * NP + col];
          out[(size_t)row * NP + col] = f2bf(v);
        }
      }
    }
  } else {
    float* out = (float*)outp;
    #pragma unroll
    for (int i = 0; i < 4; ++i) {
      #pragma unroll
      for (int jj = 0; jj < 4; ++jj) {
        int col = n0 + wc * 64 + jj * 16 + l15;
        int unit = col >> 2, gt = col & 3;
        float bias = (unit < HID) ? (b_ih[gt * HID + unit] + b_hh[gt * HID + unit]) : 0.f;
        #pragma unroll
        for (int r = 0; r < 4; ++r) {
          int row = m0 + wr * 64 + i * 16 + l4 * 4 + r;
          out[(size_t)row * NP + col] = acc[i][jj][r] + bias;
        }
      }
    }
  }
}

// ---------- cooperative LSTM recurrence: 192 blocks x 256 thr ----------
// Block nb owns gate cols [32nb,32nb+32) == hidden units [8nb,8nb+8).
// h[t] staged global->LDS via async global_load_lds DMA ring (6 x 8KB chunks,
// counted vmcnt(8), raw s_barrier) -- deep pipeline without VGPR cost.
// Global source addresses pre-permuted (cg = (s&3)^(row&3)) so linear LDS dest
// gives 64B-coalesced L2 reads and <=4-way-conflict MFMA a-reads.
// c-state lives in registers across all 200 steps; gates_x loaded per-thread
// direct to registers. W slice resident in LDS (96KB, XOR-swizzled).
__global__ __launch_bounds__(256)
void lstm_coop(const unsigned short* __restrict__ gates_x,
               const unsigned short* __restrict__ Whh,
               unsigned short* __restrict__ hs,
               float* __restrict__ cws) {
  extern __shared__ char smem[];
  // [0,98304): W slice bf16 [32][KH] XOR-swizzled ((row&7)<<4 on 16B units)
  // [98304,147456): h DMA ring, 6 bufs x 8192B; gsh f32[128][32] (16KB) aliases bufs 0-1
  char* hb = smem + 98304;
  float* gsh = (float*)(smem + 98304);

  const int tid = threadIdx.x;
  const int nb = blockIdx.x;
  const int n0 = nb * 32;

  for (int c = tid; c < 32 * 192; c += 256) {   // preload W slice once
    int row = c / 192;
    int kb = (c - row * 192) * 16;
    uint4 v = *(const uint4*)((const char*)Whh + ((size_t)(n0 + row) * KH) * 2 + kb);
    *(uint4*)(smem + row * 3072 + (kb ^ ((row & 7) << 4))) = v;
  }
  __syncthreads();

  const int w = tid >> 6, lane = tid & 63;
  const int l15 = lane & 15, l4 = lane >> 4;
  const int mrow = w * 32;
  const int sw = (l15 & 7) << 4;
  const char* b0base = smem + l15 * 3072;
  const char* b1base = smem + (16 + l15) * 3072;

  // staging constants: slot s0=tid -> row=tid>>2, cg=(tid&3)^(row&3); s1=256+tid -> row+64, same cg
  const int srow = tid >> 2;
  const int scg  = (tid & 3) ^ (srow & 3);
  // MFMA a-read offsets within an 8KB chunk buf ([row][64B], cols XOR-placed)
  const int ar0 = mrow + l15;
  const int aoff0 = ar0 * 64 + ((l4 * 16) ^ ((ar0 & 3) << 4));
  const int aoff1 = (ar0 + 16) * 64 + ((l4 * 16) ^ ((ar0 & 3) << 4));

  // c-state in registers for all 200 steps
  float cr[4];
  #pragma unroll
  for (int q = 0; q < 4; ++q) {
    int it = q * 256 + tid;
    int m = it >> 3, dj = it & 7;
    cr[q] = cws[(size_t)m * KH + ((n0 >> 2) + dj)];
  }

  cg::grid_group grid = cg::this_grid();

  for (int t = 0; t < SEQ; ++t) {
    const char* hsrc = (const char*)hs + (size_t)t * BATCH * KH * 2;
    const char* gbase = (const char*)gates_x + (size_t)t * BATCH * NP * 2;

    // per-thread gate values -> registers (consumed in pointwise)
    uint2 g4[4];
    #pragma unroll
    for (int q = 0; q < 4; ++q) {
      int it = q * 256 + tid;
      int m = it >> 3, dj = it & 7;
      g4[q] = *(const uint2*)(gbase + ((size_t)m * NP + n0 + dj * 4) * 2);
    }

    const char* sbase0 = hsrc + (size_t)srow * KH * 2 + scg * 16;
    const char* sbase1 = hsrc + (size_t)(64 + srow) * KH * 2 + scg * 16;

    // prologue: chunks 0..4 in flight
    #pragma unroll
    for (int kc = 0; kc < 5; ++kc) {
      char* b = hb + kc * 8192;
      __builtin_amdgcn_global_load_lds((gvoid*)(sbase0 + kc * 64), (lvoid*)(b + tid * 16), 16, 0, 0);
      __builtin_amdgcn_global_load_lds((gvoid*)(sbase1 + kc * 64), (lvoid*)(b + 4096 + tid * 16), 16, 0, 0);
    }

    f32x4 acc00 = {0.f,0.f,0.f,0.f}, acc01 = {0.f,0.f,0.f,0.f};
    f32x4 acc10 = {0.f,0.f,0.f,0.f}, acc11 = {0.f,0.f,0.f,0.f};

    #pragma unroll
    for (int kt = 0; kt < 48; ++kt) {
      int rem = 47 - kt;
      wait_vm(rem >= 4 ? 8 : 2 * rem);          // chunk kt complete (counted, never over-drain)
      __builtin_amdgcn_s_barrier();
      __builtin_amdgcn_sched_barrier(0);
      if (kt + 5 < 48) {                         // refill ring (writes buf (kt+5)%6, readers done at bar)
        char* b = hb + ((kt + 5) % 6) * 8192;
        __builtin_amdgcn_global_load_lds((gvoid*)(sbase0 + (kt + 5) * 64), (lvoid*)(b + tid * 16), 16, 0, 0);
        __builtin_amdgcn_global_load_lds((gvoid*)(sbase1 + (kt + 5) * 64), (lvoid*)(b + 4096 + tid * 16), 16, 0, 0);
      }
      const char* buf = hb + (kt % 6) * 8192;
      bf16x8 a0 = *(const bf16x8*)(buf + aoff0);
      bf16x8 a1 = *(const bf16x8*)(buf + aoff1);
      int koff = kt * 64 + l4 * 16;
      bf16x8 b0 = *(const bf16x8*)(b0base + (koff ^ sw));
      bf16x8 b1 = *(const bf16x8*)(b1base + (koff ^ sw));
      acc00 = __builtin_amdgcn_mfma_f32_16x16x32_bf16(a0, b0, acc00, 0, 0, 0);
      acc01 = __builtin_amdgcn_mfma_f32_16x16x32_bf16(a0, b1, acc01, 0, 0, 0);
      acc10 = __builtin_amdgcn_mfma_f32_16x16x32_bf16(a1, b0, acc10, 0, 0, 0);
      acc11 = __builtin_amdgcn_mfma_f32_16x16x32_bf16(a1, b1, acc11, 0, 0, 0);
    }
    __syncthreads();   // all chunk reads done; ring free for gsh alias

    // scatter acc -> gsh (XOR-swizzled, conflict-free both sides)
    #pragma unroll
    for (int r = 0; r < 4; ++r) {
      int row0 = mrow + l4 * 4 + r;
      int row1 = row0 + 16;
      gsh[row0 * 32 + ( l15       ^ ((row0 & 7) << 2))] = acc00[r];
      gsh[row0 * 32 + ((16 + l15) ^ ((row0 & 7) << 2))] = acc01[r];
      gsh[row1 * 32 + ( l15       ^ ((row1 & 7) << 2))] = acc10[r];
      gsh[row1 * 32 + ((16 + l15) ^ ((row1 & 7) << 2))] = acc11[r];
    }
    __syncthreads();

    unsigned short* hnext = hs + (size_t)(t + 1) * BATCH * KH;
    #pragma unroll
    for (int q = 0; q < 4; ++q) {
      int it = q * 256 + tid;
      int m = it >> 3, dj = it & 7;
      f32x4 gv = *(const f32x4*)&gsh[m * 32 + ((dj * 4) ^ ((m & 7) << 2))];
      float gi = gv[0] + bf2f((unsigned short)(g4[q].x & 0xffffu));
      float gf = gv[1] + bf2f((unsigned short)(g4[q].x >> 16));
      float gg = gv[2] + bf2f((unsigned short)(g4[q].y & 0xffffu));
      float go = gv[3] + bf2f((unsigned short)(g4[q].y >> 16));
      float cn = sigm(gf) * cr[q] + sigm(gi) * tanh_f(gg);
      float hn = sigm(go) * tanh_f(cn);
      cr[q] = cn;
      hnext[(size_t)m * KH + (n0 >> 2) + dj] = f2bf(hn);
    }
    grid.sync();
  }

  // write final c once
  #pragma unroll
  for (int q = 0; q < 4; ++q) {
    int it = q * 256 + tid;
    int m = it >> 3, dj = it & 7;
    cws[(size_t)m * KH + ((n0 >> 2) + dj)] = cr[q];
  }
}

// ---------- output projection + log_softmax ----------
__global__ __launch_bounds__(256)
void out_softmax(const unsigned short* __restrict__ hs1,
                 const unsigned short* __restrict__ Wout,
                 const float* __restrict__ b_out,
                 float* __restrict__ pred) {
  const int tid = threadIdx.x;
  const int blk = blockIdx.x;   // 200
  const int w = tid >> 6, lane = tid & 63;
  const int l15 = lane & 15, l4 = lane >> 4;
  const int m0 = blk * 128 + w * 32;

  f32x4 acc[2][7] = {};
  const char* a0p = (const char*)hs1 + ((size_t)(m0 + l15)) * KH * 2 + l4 * 16;
  const char* a1p = a0p + (size_t)16 * KH * 2;
  const char* bp = (const char*)Wout + ((size_t)l15) * KH * 2 + l4 * 16;

  for (int kk = 0; kk < KH / 32; ++kk) {
    bf16x8 a0 = *(const bf16x8*)(a0p + kk * 64);
    bf16x8 a1 = *(const bf16x8*)(a1p + kk * 64);
    #pragma unroll
    for (int ni = 0; ni < 7; ++ni) {
      bf16x8 b = *(const bf16x8*)(bp + (size_t)ni * 16 * KH * 2 + kk * 64);
      acc[0][ni] = __builtin_amdgcn_mfma_f32_16x16x32_bf16(a0, b, acc[0][ni], 0, 0, 0);
      acc[1][ni] = __builtin_amdgcn_mfma_f32_16x16x32_bf16(a1, b, acc[1][ni], 0, 0, 0);
    }
  }

  #pragma unroll
  for (int mi = 0; mi < 2; ++mi) {
    #pragma unroll
    for (int r = 0; r < 4; ++r) {
      float vals[7];
      float mx = -3.0e38f;
      #pragma unroll
      for (int ni = 0; ni < 7; ++ni) {
        int col = ni * 16 + l15;
        float v = acc[mi][ni][r];
        if (col < PRED) { v += b_out[col]; mx = fmaxf(mx, v); }
        vals[ni] = v;
      }
      #pragma unroll
      for (int s = 1; s < 16; s <<= 1) mx = fmaxf(mx, __shfl_xor(mx, s));
      float se = 0.f;
      #pragma unroll
      for (int ni = 0; ni < 7; ++ni) {
        int col = ni * 16 + l15;
        if (col < PRED) se += __expf(vals[ni] - mx);
      }
      #pragma unroll
      for (int s = 1; s < 16; s <<= 1) se += __shfl_xor(se, s);
      float lse = __logf(se) + mx;
      int row = m0 + mi * 16 + l4 * 4 + r;
      #pragma unroll
      for (int ni = 0; ni < 7; ++ni) {
        int col = ni * 16 + l15;
        if (col < PRED) pred[(size_t)row * PRED + col] = vals[ni] - lse;
      }
    }
  }
}

__global__ __launch_bounds__(256) void k_hc_out(const unsigned short* __restrict__ hs200,
                                                const float* __restrict__ cws,
                                                float* __restrict__ out_h,
                                                float* __restrict__ out_c) {
  int idx = blockIdx.x * 256 + threadIdx.x;   // 128*KH
  int b = idx / KH, j = idx - b * KH;
  if (b >= BATCH || j >= HID) return;
  out_h[(size_t)b * HID + j] = bf2f(hs200[(size_t)b * KH + j]);
  out_c[(size_t)b * HID + j] = cws[(size_t)b * KH + j];
}

// ---------- workspace layout (bytes) ----------
#define OFF_GX    0ull                     /* bf16 [MR][NP]      314,572,800 */
#define OFF_WIHT  314572800ull             /* bf16 [NP][KX]       14,942,208 */
#define OFF_WIHA  329515008ull             /* bf16 [NP][KA]        3,932,160 */
#define OFF_WHH   333447168ull             /* bf16 [NP][KH]       18,874,368 */
#define OFF_WOUT  352321536ull             /* bf16 [NOUT][KH]        344,064 */
#define OFF_NTT   352665600ull             /* f32  [128][NP]       3,145,728 */
#define OFF_NTEB  355811328ull             /* bf16 [128][KA]          81,920 */
#define OFF_CWS   355893248ull             /* f32  [128][KH]         786,432 */
#define OFF_HS    356679680ull             /* bf16 [201][128][KH] 79,036,416 */
#define OFF_X     356679680ull             /* bf16 [MR][KX] aliases HS (dead before HS init) */

extern "C" void kernel_launch(void* const* d_in, const int* in_sizes, int n_in,
                              void* d_out, int out_size, void* d_ws, size_t ws_size,
                              hipStream_t stream) {
  (void)in_sizes; (void)n_in; (void)out_size; (void)ws_size;
  const int*   nt_in  = (const int*)  d_in[0];
  const int*   t_in   = (const int*)  d_in[1];
  const float* h0     = (const float*)d_in[2];
  const float* c0     = (const float*)d_in[3];
  const float* fv     = (const float*)d_in[4];
  const float* nt_emb = (const float*)d_in[5];
  const float* t_emb  = (const float*)d_in[6];
  const float* W_ih   = (const float*)d_in[7];
  const float* W_hh   = (const float*)d_in[8];
  const float* b_ih   = (const float*)d_in[9];
  const float* b_hh   = (const float*)d_in[10];
  const float* W_out  = (const float*)d_in[11];
  const float* b_out  = (const float*)d_in[12];

  char* ws = (char*)d_ws;
  unsigned short* gx    = (unsigned short*)(ws + OFF_GX);
  unsigned short* wih_t = (unsigned short*)(ws + OFF_WIHT);
  unsigned short* wih_a = (unsigned short*)(ws + OFF_WIHA);
  unsigned short* whh   = (unsigned short*)(ws + OFF_WHH);
  unsigned short* wout  = (unsigned short*)(ws + OFF_WOUT);
  float*          ntt   = (float*)(ws + OFF_NTT);
  unsigned short* nteb  = (unsigned short*)(ws + OFF_NTEB);
  float*          cws   = (float*)(ws + OFF_CWS);
  unsigned short* hs    = (unsigned short*)(ws + OFF_HS);
  unsigned short* X     = (unsigned short*)(ws + OFF_X);

  float* pred  = (float*)d_out;
  float* out_h = pred + (size_t)MR * PRED;
  float* out_c = out_h + (size_t)BATCH * HID;

  k_wih_t<<<3648, 256, 0, stream>>>(W_ih, wih_t);
  k_wih_a<<<960, 256, 0, stream>>>(W_ih, wih_a);
  k_whh<<<4608, 256, 0, stream>>>(W_hh, whh);
  k_wout<<<84, 256, 0, stream>>>(W_out, wout);
  k_ntemb<<<20, 256, 0, stream>>>(nt_emb, nteb);
  gemm_bt<KA, 1><<<48, 256, 0, stream>>>(nteb, wih_a, ntt, 1, nullptr, nullptr, b_ih, b_hh);
  k_xgather<<<15200, 256, 0, stream>>>(t_in, t_emb, X);
  gemm_bt<KX, 0><<<9600, 256, 0, stream>>>(X, wih_t, gx, 200, nt_in, ntt, nullptr, nullptr);
  k_init<<<768, 256, 0, stream>>>(h0, c0, fv, hs, cws);

  hipFuncSetAttribute((const void*)lstm_coop, hipFuncAttributeMaxDynamicSharedMemorySize, 147456);
  void* args[] = { (void*)&gx, (void*)&whh, (void*)&hs, (void*)&cws };
  hipLaunchCooperativeKernel((void*)lstm_coop, dim3(192), dim3(256), args, 147456, stream);

  out_softmax<<<200, 256, 0, stream>>>(hs + (size_t)BATCH * KH, wout, b_out, pred);
  k_hc_out<<<768, 256, 0, stream>>>(hs + (size_t)SEQ * BATCH * KH, cws, out_h, out_c);
}